// Round 1
// baseline (387.419 us; speedup 1.0000x reference)
//
#include <hip/hip_runtime.h>

// Problem constants
#define B_    4
#define CIN_  64
#define COUT_ 64
#define H_    128
#define W_    128
#define HW_   (H_*W_)
#define K2_   9
#define NOFF_ 18     // 2*G*K*K offset channels
#define OG_   32     // output channels per thread in deform kernel

// ---------------------------------------------------------------------------
// Kernel A: transpose w_deform (o, c, ky, kx) -> wt[k2][c][o]
// so the deform kernel's weight reads are consecutive & uniform (s_load_dwordx16).
// ---------------------------------------------------------------------------
__global__ void transpose_w(const float* __restrict__ w, float* __restrict__ wt) {
    int t = blockIdx.x * 256 + threadIdx.x;      // t = (k2*64 + c)*64 + o
    if (t >= K2_ * CIN_ * COUT_) return;
    int o  = t & 63;
    int c  = (t >> 6) & 63;
    int k2 = t >> 12;
    wt[t] = w[(o * CIN_ + c) * K2_ + k2];
}

// ---------------------------------------------------------------------------
// Kernel B: offset = conv3x3(x, w_offset), pad 1, stride 1.
// One thread per output element. Block = one row (128 threads).
// blockIdx = (oh, oc, b). Weight indices are block-uniform -> scalar loads.
// ---------------------------------------------------------------------------
__global__ __launch_bounds__(128) void offset_conv(const float* __restrict__ x,
                                                   const float* __restrict__ w,
                                                   float* __restrict__ offs) {
    const int ow = threadIdx.x;
    const int oh = blockIdx.x;
    const int oc = blockIdx.y;
    const int b  = blockIdx.z;

    const float* xb = x + b * CIN_ * HW_;
    const float* wb = w + oc * CIN_ * K2_;

    float acc = 0.f;
    for (int c = 0; c < CIN_; ++c) {
        const float* xc = xb + c * HW_;
        const float* wc = wb + c * K2_;
        #pragma unroll
        for (int ky = 0; ky < 3; ++ky) {
            int iy = oh - 1 + ky;
            if (iy < 0 || iy >= H_) continue;          // block-uniform branch
            const float* row = xc + iy * W_;
            #pragma unroll
            for (int kx = 0; kx < 3; ++kx) {
                int ix = ow - 1 + kx;
                float xv = (ix >= 0 && ix < W_) ? row[ix] : 0.f;
                acc = fmaf(xv, wc[ky * 3 + kx], acc);
            }
        }
    }
    offs[((b * NOFF_ + oc) * H_ + oh) * W_ + ow] = acc;
}

// ---------------------------------------------------------------------------
// Kernel C: deformable sampling + contraction.
// One thread = one output pixel x 32 output channels (gridDim.y = 2 groups).
// Per k2: read (dy,dx), build 4 corner weights (zeroed when out-of-bounds,
// indices clamped -> branchless), then loop c: gather bilinear v once,
// 32 fmaf with uniform (scalar-loaded) weights from wt[k2][c][o].
// ---------------------------------------------------------------------------
__global__ __launch_bounds__(256) void deform_kernel(const float* __restrict__ x,
                                                     const float* __restrict__ offs,
                                                     const float* __restrict__ wt,
                                                     float* __restrict__ out) {
    const int p  = blockIdx.x * 256 + threadIdx.x;  // pixel id in [0, B*H*W)
    const int og = blockIdx.y;                      // output-channel group (0/1)
    const int ow = p & (W_ - 1);
    const int oh = (p >> 7) & (H_ - 1);
    const int b  = p >> 14;

    float acc[OG_];
    #pragma unroll
    for (int i = 0; i < OG_; ++i) acc[i] = 0.f;

    const float* xb = x + b * CIN_ * HW_;
    const float* ob = offs + b * NOFF_ * HW_ + oh * W_ + ow;

    for (int k2 = 0; k2 < K2_; ++k2) {
        float dy = ob[(2 * k2 + 0) * HW_];
        float dx = ob[(2 * k2 + 1) * HW_];
        int   ky = k2 / 3;
        int   kx = k2 - ky * 3;

        float py = (float)(oh - 1 + ky) + dy;
        float px = (float)(ow - 1 + kx) + dx;
        float y0f = floorf(py), x0f = floorf(px);
        float ly = py - y0f,    lx = px - x0f;
        int   y0 = (int)y0f,    x0 = (int)x0f;
        int   y1 = y0 + 1,      x1 = x0 + 1;

        float wy0 = 1.f - ly, wx0 = 1.f - lx;
        float w00 = wy0 * wx0, w01 = wy0 * lx, w10 = ly * wx0, w11 = ly * lx;

        // zero weights of out-of-bounds corners; clamp indices for safe loads
        bool vy0 = (y0 >= 0) & (y0 < H_);
        bool vy1 = (y1 >= 0) & (y1 < H_);
        bool vx0 = (x0 >= 0) & (x0 < W_);
        bool vx1 = (x1 >= 0) & (x1 < W_);
        if (!(vy0 & vx0)) w00 = 0.f;
        if (!(vy0 & vx1)) w01 = 0.f;
        if (!(vy1 & vx0)) w10 = 0.f;
        if (!(vy1 & vx1)) w11 = 0.f;

        int y0c = min(max(y0, 0), H_ - 1);
        int y1c = min(max(y1, 0), H_ - 1);
        int x0c = min(max(x0, 0), W_ - 1);
        int x1c = min(max(x1, 0), W_ - 1);

        int o00 = y0c * W_ + x0c;
        int o01 = y0c * W_ + x1c;
        int o10 = y1c * W_ + x0c;
        int o11 = y1c * W_ + x1c;

        const float* wk = wt + k2 * CIN_ * COUT_ + og * OG_;  // wt[k2][c][o]
        const float* xc = xb;
        for (int c = 0; c < CIN_; ++c, xc += HW_) {
            float v = w00 * xc[o00] + w01 * xc[o01] + w10 * xc[o10] + w11 * xc[o11];
            const float* wc = wk + c * COUT_;
            #pragma unroll
            for (int oi = 0; oi < OG_; ++oi)
                acc[oi] = fmaf(v, wc[oi], acc[oi]);
        }
    }

    float* outp = out + ((b * COUT_ + og * OG_) * H_ + oh) * W_ + ow;
    #pragma unroll
    for (int oi = 0; oi < OG_; ++oi) outp[oi * HW_] = acc[oi];
}

// ---------------------------------------------------------------------------
extern "C" void kernel_launch(void* const* d_in, const int* in_sizes, int n_in,
                              void* d_out, int out_size, void* d_ws, size_t ws_size,
                              hipStream_t stream) {
    const float* x        = (const float*)d_in[0];  // (4, 64, 128, 128)
    const float* w_offset = (const float*)d_in[1];  // (18, 64, 3, 3)
    const float* w_deform = (const float*)d_in[2];  // (64, 64, 3, 3)
    float* out = (float*)d_out;                     // (4, 64, 128, 128)

    float* offs = (float*)d_ws;                       // B*18*H*W = 1179648 floats
    float* wt   = offs + (size_t)B_ * NOFF_ * HW_;    // 9*64*64   = 36864 floats

    transpose_w<<<(K2_ * CIN_ * COUT_ + 255) / 256, 256, 0, stream>>>(w_deform, wt);
    offset_conv<<<dim3(H_, NOFF_, B_), 128, 0, stream>>>(x, w_offset, offs);
    deform_kernel<<<dim3((B_ * HW_) / 256, COUT_ / OG_), 256, 0, stream>>>(x, offs, wt, out);
}

// Round 2
// 293.022 us; speedup vs baseline: 1.3221x; 1.3221x over previous
//
#include <hip/hip_runtime.h>

// Problem constants
#define B_    4
#define CIN_  64
#define COUT_ 64
#define H_    128
#define W_    128
#define HW_   (H_*W_)
#define K2_   9
#define NOFF_ 18     // 2*G*K*K offset channels
#define OG_   32     // output channels per thread in deform kernel

// ---------------------------------------------------------------------------
// Kernel A: weight prep.
//  wt_d[k2][c][o]   <- w_deform[o][c][k2]   (36864 floats)
//  wt_o[c][oc][k2]  <- w_offset[oc][c][k2]  (10368 floats)
// Both give block-uniform consecutive weight reads in the hot kernels.
// ---------------------------------------------------------------------------
__global__ void prep_weights(const float* __restrict__ wd,
                             const float* __restrict__ wo,
                             float* __restrict__ wt_d,
                             float* __restrict__ wt_o) {
    int t = blockIdx.x * 256 + threadIdx.x;
    if (t < K2_ * CIN_ * COUT_) {
        int o  = t & 63;
        int c  = (t >> 6) & 63;
        int k2 = t >> 12;
        wt_d[t] = wd[(o * CIN_ + c) * K2_ + k2];
    } else {
        int u = t - K2_ * CIN_ * COUT_;
        if (u >= CIN_ * NOFF_ * K2_) return;
        int k2 = u % 9;
        int oc = (u / 9) % NOFF_;
        int c  = u / (9 * NOFF_);
        wt_o[u] = wo[(oc * CIN_ + c) * K2_ + k2];
    }
}

// ---------------------------------------------------------------------------
// Kernel B: offset = conv3x3(x, w_offset), pad 1, stride 1.
// Thread = one pixel x 9 offset channels (gridDim.y = 2 groups -> 2048 waves).
// Per c: 9 x-loads (branchless zero-pad) feed 81 independent FMAs into 9 accs.
// Weights are block-uniform -> scalar loads from wt_o[c][grp*9..][9].
// ---------------------------------------------------------------------------
__global__ __launch_bounds__(256, 2) void offset_conv2(const float* __restrict__ x,
                                                       const float* __restrict__ wt_o,
                                                       float* __restrict__ offs) {
    const int p   = blockIdx.x * 256 + threadIdx.x;   // pixel id
    const int grp = blockIdx.y;                        // 0/1 -> channels 0-8 / 9-17
    const int ow  = p & (W_ - 1);
    const int oh  = (p >> 7) & (H_ - 1);
    const int b   = p >> 14;

    float acc[9];
    #pragma unroll
    for (int i = 0; i < 9; ++i) acc[i] = 0.f;

    const float* xb = x + b * CIN_ * HW_;

    #pragma unroll 2
    for (int c = 0; c < CIN_; ++c) {
        const float* xc = xb + c * HW_;
        float xv[9];
        #pragma unroll
        for (int ky = 0; ky < 3; ++ky) {
            int iy = oh - 1 + ky;
            bool vy = (unsigned)iy < (unsigned)H_;
            int iyc = min(max(iy, 0), H_ - 1);
            #pragma unroll
            for (int kx = 0; kx < 3; ++kx) {
                int ix = ow - 1 + kx;
                bool vx = (unsigned)ix < (unsigned)W_;
                int ixc = min(max(ix, 0), W_ - 1);
                float v = xc[iyc * W_ + ixc];
                xv[ky * 3 + kx] = (vy && vx) ? v : 0.f;
            }
        }
        const float* wc = wt_o + (c * NOFF_ + grp * 9) * K2_;  // 81 consecutive, uniform
        #pragma unroll
        for (int oc = 0; oc < 9; ++oc)
            #pragma unroll
            for (int t = 0; t < 9; ++t)
                acc[oc] = fmaf(xv[t], wc[oc * 9 + t], acc[oc]);
    }

    float* op = offs + ((b * NOFF_ + grp * 9) * HW_) + (p & (HW_ - 1));
    #pragma unroll
    for (int oc = 0; oc < 9; ++oc) op[oc * HW_] = acc[oc];
}

// ---------------------------------------------------------------------------
// Kernel C: deformable sampling + contraction.
// Thread = one pixel x 32 output channels. c-loop unrolled x4 so 16 gather
// loads are in flight per stall window (latency fix for R1's 29% VALUBusy).
// ---------------------------------------------------------------------------
__global__ __launch_bounds__(256, 2) void deform_kernel(const float* __restrict__ x,
                                                        const float* __restrict__ offs,
                                                        const float* __restrict__ wt,
                                                        float* __restrict__ out) {
    const int p  = blockIdx.x * 256 + threadIdx.x;  // pixel id in [0, B*H*W)
    const int og = blockIdx.y;                      // output-channel group (0/1)
    const int ow = p & (W_ - 1);
    const int oh = (p >> 7) & (H_ - 1);
    const int b  = p >> 14;

    float acc[OG_];
    #pragma unroll
    for (int i = 0; i < OG_; ++i) acc[i] = 0.f;

    const float* xb = x + b * CIN_ * HW_;
    const float* ob = offs + b * NOFF_ * HW_ + oh * W_ + ow;

    for (int k2 = 0; k2 < K2_; ++k2) {
        float dy = ob[(2 * k2 + 0) * HW_];
        float dx = ob[(2 * k2 + 1) * HW_];
        int   ky = k2 / 3;
        int   kx = k2 - ky * 3;

        float py = (float)(oh - 1 + ky) + dy;
        float px = (float)(ow - 1 + kx) + dx;
        float y0f = floorf(py), x0f = floorf(px);
        float ly = py - y0f,    lx = px - x0f;
        int   y0 = (int)y0f,    x0 = (int)x0f;
        int   y1 = y0 + 1,      x1 = x0 + 1;

        float wy0 = 1.f - ly, wx0 = 1.f - lx;
        float w00 = wy0 * wx0, w01 = wy0 * lx, w10 = ly * wx0, w11 = ly * lx;

        bool vy0 = (y0 >= 0) & (y0 < H_);
        bool vy1 = (y1 >= 0) & (y1 < H_);
        bool vx0 = (x0 >= 0) & (x0 < W_);
        bool vx1 = (x1 >= 0) & (x1 < W_);
        if (!(vy0 & vx0)) w00 = 0.f;
        if (!(vy0 & vx1)) w01 = 0.f;
        if (!(vy1 & vx0)) w10 = 0.f;
        if (!(vy1 & vx1)) w11 = 0.f;

        int y0c = min(max(y0, 0), H_ - 1);
        int y1c = min(max(y1, 0), H_ - 1);
        int x0c = min(max(x0, 0), W_ - 1);
        int x1c = min(max(x1, 0), W_ - 1);

        int o00 = y0c * W_ + x0c;
        int o01 = y0c * W_ + x1c;
        int o10 = y1c * W_ + x0c;
        int o11 = y1c * W_ + x1c;

        const float* wk = wt + k2 * CIN_ * COUT_ + og * OG_;  // wt[k2][c][o]

        #pragma unroll 4
        for (int c = 0; c < CIN_; ++c) {
            const float* xc = xb + c * HW_;
            float a00 = xc[o00];
            float a01 = xc[o01];
            float a10 = xc[o10];
            float a11 = xc[o11];
            float v = w00 * a00 + w01 * a01 + w10 * a10 + w11 * a11;
            const float* wc = wk + c * COUT_;
            #pragma unroll
            for (int oi = 0; oi < OG_; ++oi)
                acc[oi] = fmaf(v, wc[oi], acc[oi]);
        }
    }

    float* outp = out + ((b * COUT_ + og * OG_) * H_ + oh) * W_ + ow;
    #pragma unroll
    for (int oi = 0; oi < OG_; ++oi) outp[oi * HW_] = acc[oi];
}

// ---------------------------------------------------------------------------
extern "C" void kernel_launch(void* const* d_in, const int* in_sizes, int n_in,
                              void* d_out, int out_size, void* d_ws, size_t ws_size,
                              hipStream_t stream) {
    const float* x        = (const float*)d_in[0];  // (4, 64, 128, 128)
    const float* w_offset = (const float*)d_in[1];  // (18, 64, 3, 3)
    const float* w_deform = (const float*)d_in[2];  // (64, 64, 3, 3)
    float* out = (float*)d_out;                     // (4, 64, 128, 128)

    float* offs = (float*)d_ws;                          // B*18*H*W = 1179648 floats
    float* wt_d = offs + (size_t)B_ * NOFF_ * HW_;       // 9*64*64   = 36864 floats
    float* wt_o = wt_d + (size_t)K2_ * CIN_ * COUT_;     // 64*18*9   = 10368 floats

    int prep_elems = K2_ * CIN_ * COUT_ + CIN_ * NOFF_ * K2_;
    prep_weights<<<(prep_elems + 255) / 256, 256, 0, stream>>>(w_deform, w_offset, wt_d, wt_o);
    offset_conv2<<<dim3((B_ * HW_) / 256, 2), 256, 0, stream>>>(x, wt_o, offs);
    deform_kernel<<<dim3((B_ * HW_) / 256, COUT_ / OG_), 256, 0, stream>>>(x, offs, wt_d, out);
}

// Round 3
// 217.603 us; speedup vs baseline: 1.7804x; 1.3466x over previous
//
#include <hip/hip_runtime.h>
#include <hip/hip_bf16.h>

// Problem constants
#define B_     4
#define CIN_   64
#define COUT_  64
#define H_     128
#define W_     128
#define HW_    (H_*W_)
#define K2_    9
#define NOFF_  18      // 2*K*K offset channels
#define CSPLIT 2       // c-dim split for offset conv (partial sums)

typedef short bf16x8 __attribute__((ext_vector_type(8)));  // 8 bf16 (4 VGPRs)
typedef float f32x4  __attribute__((ext_vector_type(4)));  // MFMA C/D

// ---------------------------------------------------------------------------
// Kernel A: weight prep.
//  wt_b[o][k2*64+c]  = bf16(w_deform[o][c][k2])   -- k-contiguous for A-frags
//  wt_o[c][oc][k2]   = w_offset[oc][c][k2]        -- uniform scalar reads
// ---------------------------------------------------------------------------
__global__ void prep_weights(const float* __restrict__ wd,
                             const float* __restrict__ wo,
                             __hip_bfloat16* __restrict__ wt_b,
                             float* __restrict__ wt_o) {
    int t = blockIdx.x * 256 + threadIdx.x;
    if (t < COUT_ * 576) {
        int o = t / 576, rem = t % 576;
        int k2 = rem >> 6, c = rem & 63;
        wt_b[t] = __float2bfloat16(wd[(o * CIN_ + c) * K2_ + k2]);
    } else {
        int u = t - COUT_ * 576;
        if (u >= CIN_ * NOFF_ * K2_) return;
        int k2 = u % 9;
        int oc = (u / 9) % NOFF_;
        int c  = u / (9 * NOFF_);
        wt_o[u] = wo[(oc * CIN_ + c) * K2_ + k2];
    }
}

// ---------------------------------------------------------------------------
// Kernel B: offset conv partials. Thread = pixel x 9 offset channels.
// blockIdx.y = channel group (0/1), blockIdx.z = c-half (0/1).
// part[z][b][ch][hw] ; fused kernel sums the z partials.
// ---------------------------------------------------------------------------
__global__ __launch_bounds__(256) void offset_conv3(const float* __restrict__ x,
                                                    const float* __restrict__ wt_o,
                                                    float* __restrict__ part) {
    const int p   = blockIdx.x * 256 + threadIdx.x;   // pixel id
    const int grp = blockIdx.y;                        // 0/1 -> ch 0-8 / 9-17
    const int z   = blockIdx.z;                        // c-half
    const int ow  = p & (W_ - 1);
    const int oh  = (p >> 7) & (H_ - 1);
    const int b   = p >> 14;

    float acc[9];
    #pragma unroll
    for (int i = 0; i < 9; ++i) acc[i] = 0.f;

    const float* xb = x + (b * CIN_ + z * 32) * HW_;

    #pragma unroll 2
    for (int c = 0; c < 32; ++c) {
        const float* xc = xb + c * HW_;
        float xv[9];
        #pragma unroll
        for (int ky = 0; ky < 3; ++ky) {
            int iy = oh - 1 + ky;
            bool vy = (unsigned)iy < (unsigned)H_;
            int iyc = min(max(iy, 0), H_ - 1);
            #pragma unroll
            for (int kx = 0; kx < 3; ++kx) {
                int ix = ow - 1 + kx;
                bool vx = (unsigned)ix < (unsigned)W_;
                int ixc = min(max(ix, 0), W_ - 1);
                float v = xc[iyc * W_ + ixc];
                xv[ky * 3 + kx] = (vy && vx) ? v : 0.f;
            }
        }
        const float* wc = wt_o + ((z * 32 + c) * NOFF_ + grp * 9) * K2_;
        #pragma unroll
        for (int oc = 0; oc < 9; ++oc)
            #pragma unroll
            for (int t = 0; t < 9; ++t)
                acc[oc] = fmaf(xv[t], wc[oc * 9 + t], acc[oc]);
    }

    float* op = part + ((size_t)z * B_ * NOFF_ + b * NOFF_ + grp * 9) * HW_ + (p & (HW_ - 1));
    #pragma unroll
    for (int oc = 0; oc < 9; ++oc) op[oc * HW_] = acc[oc];
}

// ---------------------------------------------------------------------------
// Kernel C: fused sampling + MFMA contraction.
// Block = 64 pixels, 256 threads (4 waves). Per k2:
//   phase 1: thread (pix=tid&63, cq=tid>>6) samples 16 channels -> vtile LDS bf16
//   phase 2: wave w computes out[64 o][16 px] via mfma_f32_16x16x32_bf16:
//            A = wt_b (m=o, k-contig, global 16B loads, L1-hot)
//            B = vtile (n=pixel, k-contig, ds_read_b128)
// C/D: col=lane&15 = pixel -> coalesced NCHW stores.
// ---------------------------------------------------------------------------
__global__ __launch_bounds__(256) void deform_fused(const float* __restrict__ x,
                                                    const float* __restrict__ part,
                                                    const __hip_bfloat16* __restrict__ wt_b,
                                                    float* __restrict__ out) {
    __shared__ float offs_l[NOFF_ * 64];             // [ch][pixel]
    __shared__ __hip_bfloat16 vtile[64 * 72];        // [pixel][c], pad 64->72

    const int tid   = threadIdx.x;
    const int pbase = blockIdx.x * 64;               // first pixel of block
    const int b     = pbase >> 14;
    const int hw0   = pbase & (HW_ - 1);
    const int pix   = tid & 63;
    const int cq    = tid >> 6;                      // c-quarter / wave id
    const int lane  = tid & 63;
    const int quad  = lane >> 4;
    const int nl    = lane & 15;

    // stage offsets: sum CSPLIT partials into LDS
    for (int v = tid; v < NOFF_ * 64; v += 256) {
        int ch = v >> 6, pl = v & 63;
        const float* pp = part + (b * NOFF_ + ch) * HW_ + hw0 + pl;
        float s = 0.f;
        #pragma unroll
        for (int z = 0; z < CSPLIT; ++z) s += pp[(size_t)z * B_ * NOFF_ * HW_];
        offs_l[ch * 64 + pl] = s;
    }
    __syncthreads();

    const int hw = hw0 + pix;
    const int oh = hw >> 7, ow = hw & (W_ - 1);
    const float* xb = x + (b * CIN_ + cq * 16) * HW_;   // this thread's 16 channels

    f32x4 acc[4];
    #pragma unroll
    for (int mb = 0; mb < 4; ++mb) acc[mb] = (f32x4){0.f, 0.f, 0.f, 0.f};

    for (int k2 = 0; k2 < K2_; ++k2) {
        // ---- phase 1: sample 16 channels for this (pixel, k2) ----
        float dy = offs_l[(2 * k2 + 0) * 64 + pix];
        float dx = offs_l[(2 * k2 + 1) * 64 + pix];
        int ky = k2 / 3, kx = k2 - 3 * (k2 / 3);

        float py = (float)(oh - 1 + ky) + dy;
        float px = (float)(ow - 1 + kx) + dx;
        float y0f = floorf(py), x0f = floorf(px);
        float ly = py - y0f,    lx = px - x0f;
        int   y0 = (int)y0f,    x0 = (int)x0f;
        int   y1 = y0 + 1,      x1 = x0 + 1;

        float wy0 = 1.f - ly, wx0 = 1.f - lx;
        float w00 = wy0 * wx0, w01 = wy0 * lx, w10 = ly * wx0, w11 = ly * lx;

        bool vy0 = (unsigned)y0 < (unsigned)H_;
        bool vy1 = (unsigned)y1 < (unsigned)H_;
        bool vx0 = (unsigned)x0 < (unsigned)W_;
        bool vx1 = (unsigned)x1 < (unsigned)W_;
        if (!(vy0 & vx0)) w00 = 0.f;
        if (!(vy0 & vx1)) w01 = 0.f;
        if (!(vy1 & vx0)) w10 = 0.f;
        if (!(vy1 & vx1)) w11 = 0.f;

        int y0c = min(max(y0, 0), H_ - 1);
        int y1c = min(max(y1, 0), H_ - 1);
        int x0c = min(max(x0, 0), W_ - 1);
        int x1c = min(max(x1, 0), W_ - 1);

        int o00 = y0c * W_ + x0c;
        int o01 = y0c * W_ + x1c;
        int o10 = y1c * W_ + x0c;
        int o11 = y1c * W_ + x1c;

        __hip_bfloat16* vrow = vtile + pix * 72 + cq * 16;
        #pragma unroll
        for (int t = 0; t < 8; ++t) {
            const float* xa = xb + (2 * t) * HW_;
            const float* xc = xa + HW_;
            float va = w00 * xa[o00] + w01 * xa[o01] + w10 * xa[o10] + w11 * xa[o11];
            float vb = w00 * xc[o00] + w01 * xc[o01] + w10 * xc[o10] + w11 * xc[o11];
            *(__hip_bfloat162*)&vrow[2 * t] = __float22bfloat162_rn(make_float2(va, vb));
        }
        __syncthreads();

        // ---- phase 2: MFMA over this k2's 64-wide K slice ----
        #pragma unroll
        for (int kb = 0; kb < 2; ++kb) {
            bf16x8 bfr = *(const bf16x8*)&vtile[(cq * 16 + nl) * 72 + kb * 32 + quad * 8];
            #pragma unroll
            for (int mb = 0; mb < 4; ++mb) {
                bf16x8 afr = *(const bf16x8*)(wt_b + (mb * 16 + nl) * 576 + k2 * 64 + kb * 32 + quad * 8);
                acc[mb] = __builtin_amdgcn_mfma_f32_16x16x32_bf16(afr, bfr, acc[mb], 0, 0, 0);
            }
        }
        __syncthreads();   // protect vtile before next k2's writes
    }

    // epilogue: C/D col = pixel, row = o_local = quad*4 + r
    #pragma unroll
    for (int mb = 0; mb < 4; ++mb) {
        #pragma unroll
        for (int r = 0; r < 4; ++r) {
            int o = mb * 16 + quad * 4 + r;
            out[(b * COUT_ + o) * HW_ + hw0 + cq * 16 + nl] = acc[mb][r];
        }
    }
}

// ---------------------------------------------------------------------------
extern "C" void kernel_launch(void* const* d_in, const int* in_sizes, int n_in,
                              void* d_out, int out_size, void* d_ws, size_t ws_size,
                              hipStream_t stream) {
    const float* x        = (const float*)d_in[0];  // (4, 64, 128, 128)
    const float* w_offset = (const float*)d_in[1];  // (18, 64, 3, 3)
    const float* w_deform = (const float*)d_in[2];  // (64, 64, 3, 3)
    float* out = (float*)d_out;                     // (4, 64, 128, 128)

    float* part = (float*)d_ws;                                    // 2 * 4*18*HW floats
    float* wt_o = part + (size_t)CSPLIT * B_ * NOFF_ * HW_;        // 64*18*9 floats
    __hip_bfloat16* wt_b = (__hip_bfloat16*)(wt_o + CIN_ * NOFF_ * K2_);  // 64*576 bf16

    int prep_elems = COUT_ * 576 + CIN_ * NOFF_ * K2_;
    prep_weights<<<(prep_elems + 255) / 256, 256, 0, stream>>>(w_deform, w_offset, wt_b, wt_o);
    offset_conv3<<<dim3((B_ * HW_) / 256, 2, CSPLIT), 256, 0, stream>>>(x, wt_o, part);
    deform_fused<<<dim3((B_ * HW_) / 64), 256, 0, stream>>>(x, part, wt_b, out);
}

// Round 4
// 186.120 us; speedup vs baseline: 2.0816x; 1.1692x over previous
//
#include <hip/hip_runtime.h>
#include <hip/hip_bf16.h>

// Problem constants
#define B_    4
#define CIN_  64
#define COUT_ 64
#define H_    128
#define W_    128
#define HW_   (H_*W_)
#define K2_   9
#define NOFF_ 18

// x tile in LDS: rows oh-2..oh+2, cols ow0-3..ow0+66, all 64 channels (bf16)
#define TROWS 5
#define TCOLS 70
#define CPAD  72    // channel pad: 144B row stride = 16B-aligned + bank-spread

typedef short bf16x8 __attribute__((ext_vector_type(8)));  // MFMA A/B frag
typedef float f32x4  __attribute__((ext_vector_type(4)));  // MFMA C/D

__device__ __forceinline__ float bf2f(short s) {
    union { unsigned u; float f; } z;
    z.u = ((unsigned)(unsigned short)s) << 16;
    return z.f;
}

// ---------------------------------------------------------------------------
// Prep: bf16 weights, k-contiguous for MFMA A-fragments.
//  wt_b [o<64][k2*64+c]  = w_deform[o][c][k2]
//  wt_ob[oc<32][t*64+c]  = w_offset[oc][c][t]  (rows 18..31 zero-padded)
// ---------------------------------------------------------------------------
__global__ void prep_weights(const float* __restrict__ wd,
                             const float* __restrict__ wo,
                             __hip_bfloat16* __restrict__ wt_b,
                             __hip_bfloat16* __restrict__ wt_ob) {
    int t = blockIdx.x * 256 + threadIdx.x;
    if (t < COUT_ * 576) {
        int o = t / 576, rem = t % 576;
        int k2 = rem >> 6, c = rem & 63;
        wt_b[t] = __float2bfloat16(wd[(o * CIN_ + c) * K2_ + k2]);
    } else {
        int u = t - COUT_ * 576;
        if (u >= 32 * 576) return;
        int oc = u / 576, rem = u % 576;
        int k2 = rem >> 6, c = rem & 63;
        float v = (oc < NOFF_) ? wo[(oc * CIN_ + c) * K2_ + k2] : 0.f;
        wt_ob[u] = __float2bfloat16(v);
    }
}

// ---------------------------------------------------------------------------
// Fused kernel: stage x tile -> offset conv (MFMA) -> sample (LDS) -> deform MFMA.
// Block = 64 pixels (b, oh, half-row), 256 threads = 4 waves. 2 blocks/CU (LDS).
// ---------------------------------------------------------------------------
__global__ __launch_bounds__(256) void deform_all(const float* __restrict__ x,
                                                  const __hip_bfloat16* __restrict__ wt_b,
                                                  const __hip_bfloat16* __restrict__ wt_ob,
                                                  float* __restrict__ out) {
    __shared__ __hip_bfloat16 xt[TROWS * TCOLS * CPAD];   // 50.4 KB
    __shared__ float offs_l[NOFF_ * 64];                  // 4.6 KB
    __shared__ __hip_bfloat16 vtile[2][64 * CPAD];        // 18.4 KB

    const int tid = threadIdx.x;
    const int blk = blockIdx.x;            // (b*128 + oh)*2 + half
    const int b   = blk >> 8;
    const int r2  = blk & 255;
    const int oh  = r2 >> 1;
    const int ow0 = (r2 & 1) << 6;

    // ---- stage x tile (coalesced: consecutive threads = consecutive cols) ----
    for (int i = tid; i < TROWS * TCOLS * CIN_; i += 256) {
        int c   = i / (TROWS * TCOLS);
        int rem = i - c * (TROWS * TCOLS);
        int r   = rem / TCOLS;
        int col = rem - r * TCOLS;
        int gy = oh - 2 + r;
        int gx = ow0 - 3 + col;
        float v = 0.f;
        if ((unsigned)gy < (unsigned)H_ && (unsigned)gx < (unsigned)W_)
            v = x[(b * CIN_ + c) * HW_ + gy * W_ + gx];
        xt[(r * TCOLS + col) * CPAD + c] = __float2bfloat16(v);
    }
    __syncthreads();

    const int lane = tid & 63;
    const int cq   = tid >> 6;     // wave id: n-tile (offset conv & deform), c-group (sampling)
    const int quad = lane >> 4;
    const int nl   = lane & 15;

    // ---- offset conv via MFMA: out[32 oc][64 px], K=576 (t-major: k=t*64+c) ----
    f32x4 oacc[2];
    oacc[0] = (f32x4){0.f, 0.f, 0.f, 0.f};
    oacc[1] = (f32x4){0.f, 0.f, 0.f, 0.f};
    #pragma unroll
    for (int t9 = 0; t9 < 9; ++t9) {
        int ky = t9 / 3, kx = t9 - 3 * (t9 / 3);
        #pragma unroll
        for (int kb = 0; kb < 2; ++kb) {
            // B[k][n=px]: x[b][c][oh-1+ky][ow0+px-1+kx] = xt[ky+1][px+kx+2][c]
            bf16x8 bfr = *(const bf16x8*)&xt[((ky + 1) * TCOLS + (cq * 16 + nl) + kx + 2) * CPAD + kb * 32 + quad * 8];
            #pragma unroll
            for (int mt = 0; mt < 2; ++mt) {
                bf16x8 afr = *(const bf16x8*)(wt_ob + (mt * 16 + nl) * 576 + t9 * 64 + kb * 32 + quad * 8);
                oacc[mt] = __builtin_amdgcn_mfma_f32_16x16x32_bf16(afr, bfr, oacc[mt], 0, 0, 0);
            }
        }
    }
    #pragma unroll
    for (int mt = 0; mt < 2; ++mt)
        #pragma unroll
        for (int r = 0; r < 4; ++r) {
            int oc = mt * 16 + quad * 4 + r;
            if (oc < NOFF_) offs_l[oc * 64 + cq * 16 + nl] = oacc[mt][r];
        }
    __syncthreads();

    // ---- sampling + deform MFMA ----
    const int pix = tid & 63;
    const int ow  = ow0 + pix;
    const float* xb = x + (b * CIN_ + cq * 16) * HW_;   // global fallback base

    f32x4 acc[4];
    #pragma unroll
    for (int mb = 0; mb < 4; ++mb) acc[mb] = (f32x4){0.f, 0.f, 0.f, 0.f};

    auto sample_k2 = [&](int k2, __hip_bfloat16* vdst) {
        float dy = offs_l[(2 * k2 + 0) * 64 + pix];
        float dx = offs_l[(2 * k2 + 1) * 64 + pix];
        int ky = k2 / 3, kx = k2 - 3 * (k2 / 3);

        float py = (float)(oh - 1 + ky) + dy;
        float px = (float)(ow - 1 + kx) + dx;
        float y0f = floorf(py), x0f = floorf(px);
        float ly = py - y0f,    lx = px - x0f;
        int   y0 = (int)y0f,    x0 = (int)x0f;
        int   y1 = y0 + 1,      x1 = x0 + 1;

        float wy0 = 1.f - ly, wx0 = 1.f - lx;
        float w00 = wy0 * wx0, w01 = wy0 * lx, w10 = ly * wx0, w11 = ly * lx;

        bool vy0 = (unsigned)y0 < (unsigned)H_;
        bool vy1 = (unsigned)y1 < (unsigned)H_;
        bool vx0 = (unsigned)x0 < (unsigned)W_;
        bool vx1 = (unsigned)x1 < (unsigned)W_;
        if (!(vy0 & vx0)) w00 = 0.f;
        if (!(vy0 & vx1)) w01 = 0.f;
        if (!(vy1 & vx0)) w10 = 0.f;
        if (!(vy1 & vx1)) w11 = 0.f;

        // tile coords (raw; only need validity when weight != 0)
        int ty0 = y0 - (oh - 2), ty1 = y1 - (oh - 2);
        int tx0 = x0 - (ow0 - 3), tx1 = x1 - (ow0 - 3);
        bool i00 = (unsigned)ty0 < TROWS && (unsigned)tx0 < TCOLS;
        bool i01 = (unsigned)ty0 < TROWS && (unsigned)tx1 < TCOLS;
        bool i10 = (unsigned)ty1 < TROWS && (unsigned)tx0 < TCOLS;
        bool i11 = (unsigned)ty1 < TROWS && (unsigned)tx1 < TCOLS;
        bool ok = (w00 == 0.f || i00) && (w01 == 0.f || i01) &&
                  (w10 == 0.f || i10) && (w11 == 0.f || i11);

        float v[16];
        if (ok) {
            int tyc0 = min(max(ty0, 0), TROWS - 1), tyc1 = min(max(ty1, 0), TROWS - 1);
            int txc0 = min(max(tx0, 0), TCOLS - 1), txc1 = min(max(tx1, 0), TCOLS - 1);
            int a00 = (tyc0 * TCOLS + txc0) * CPAD + cq * 16;
            int a01 = (tyc0 * TCOLS + txc1) * CPAD + cq * 16;
            int a10 = (tyc1 * TCOLS + txc0) * CPAD + cq * 16;
            int a11 = (tyc1 * TCOLS + txc1) * CPAD + cq * 16;
            bf16x8 c00a = *(const bf16x8*)&xt[a00], c00b = *(const bf16x8*)&xt[a00 + 8];
            bf16x8 c01a = *(const bf16x8*)&xt[a01], c01b = *(const bf16x8*)&xt[a01 + 8];
            bf16x8 c10a = *(const bf16x8*)&xt[a10], c10b = *(const bf16x8*)&xt[a10 + 8];
            bf16x8 c11a = *(const bf16x8*)&xt[a11], c11b = *(const bf16x8*)&xt[a11 + 8];
            #pragma unroll
            for (int j = 0; j < 8; ++j) {
                v[j]     = w00 * bf2f(c00a[j]) + w01 * bf2f(c01a[j]) + w10 * bf2f(c10a[j]) + w11 * bf2f(c11a[j]);
                v[j + 8] = w00 * bf2f(c00b[j]) + w01 * bf2f(c01b[j]) + w10 * bf2f(c10b[j]) + w11 * bf2f(c11b[j]);
            }
        } else {
            // rare global fallback (arbitrary offsets): image-clamped gather
            int y0c = min(max(y0, 0), H_ - 1), y1c = min(max(y1, 0), H_ - 1);
            int x0c = min(max(x0, 0), W_ - 1), x1c = min(max(x1, 0), W_ - 1);
            int o00 = y0c * W_ + x0c, o01 = y0c * W_ + x1c;
            int o10 = y1c * W_ + x0c, o11 = y1c * W_ + x1c;
            #pragma unroll 4
            for (int t = 0; t < 16; ++t) {
                const float* xc = xb + t * HW_;
                v[t] = w00 * xc[o00] + w01 * xc[o01] + w10 * xc[o10] + w11 * xc[o11];
            }
        }
        __hip_bfloat16* vrow = vdst + pix * CPAD + cq * 16;
        #pragma unroll
        for (int j = 0; j < 8; ++j)
            *(__hip_bfloat162*)&vrow[2 * j] = __float22bfloat162_rn(make_float2(v[2 * j], v[2 * j + 1]));
    };

    sample_k2(0, vtile[0]);
    __syncthreads();

    for (int k2 = 0; k2 < K2_; ++k2) {
        if (k2 < K2_ - 1) sample_k2(k2 + 1, vtile[(k2 + 1) & 1]);
        const __hip_bfloat16* vt = vtile[k2 & 1];
        #pragma unroll
        for (int kb = 0; kb < 2; ++kb) {
            bf16x8 bfr = *(const bf16x8*)&vt[(cq * 16 + nl) * CPAD + kb * 32 + quad * 8];
            #pragma unroll
            for (int mb = 0; mb < 4; ++mb) {
                bf16x8 afr = *(const bf16x8*)(wt_b + (mb * 16 + nl) * 576 + k2 * 64 + kb * 32 + quad * 8);
                acc[mb] = __builtin_amdgcn_mfma_f32_16x16x32_bf16(afr, bfr, acc[mb], 0, 0, 0);
            }
        }
        __syncthreads();
    }

    // epilogue: C/D col = pixel, row = quad*4 + r (verified layout)
    #pragma unroll
    for (int mb = 0; mb < 4; ++mb)
        #pragma unroll
        for (int r = 0; r < 4; ++r) {
            int o = mb * 16 + quad * 4 + r;
            out[(b * COUT_ + o) * HW_ + oh * W_ + ow0 + cq * 16 + nl] = acc[mb][r];
        }
}

// ---------------------------------------------------------------------------
extern "C" void kernel_launch(void* const* d_in, const int* in_sizes, int n_in,
                              void* d_out, int out_size, void* d_ws, size_t ws_size,
                              hipStream_t stream) {
    const float* x        = (const float*)d_in[0];  // (4, 64, 128, 128)
    const float* w_offset = (const float*)d_in[1];  // (18, 64, 3, 3)
    const float* w_deform = (const float*)d_in[2];  // (64, 64, 3, 3)
    float* out = (float*)d_out;                     // (4, 64, 128, 128)

    __hip_bfloat16* wt_b  = (__hip_bfloat16*)d_ws;        // 64*576 bf16
    __hip_bfloat16* wt_ob = wt_b + (size_t)COUT_ * 576;   // 32*576 bf16

    int prep_elems = COUT_ * 576 + 32 * 576;
    prep_weights<<<(prep_elems + 255) / 256, 256, 0, stream>>>(w_deform, w_offset, wt_b, wt_ob);
    deform_all<<<dim3(B_ * H_ * (W_ / 64)), 256, 0, stream>>>(x, wt_b, wt_ob, out);
}

// Round 5
// 136.244 us; speedup vs baseline: 2.8436x; 1.3661x over previous
//
#include <hip/hip_runtime.h>

// Problem constants
#define B_    4
#define CIN_  64
#define COUT_ 64
#define H_    128
#define W_    128
#define HW_   (H_*W_)
#define K2_   9
#define NOFF_ 18

// padded NHWC fp16 tensor: rows -2..129 (132), cols -3..132 (136), 64 ch
#define PR_   132
#define PC_   136
// x tile in LDS: rows oh-2..oh+2, cols ow0-3..ow0+66
#define TROWS 5
#define TCOLS 70
#define CPAD  72     // LDS channel stride (halfs): 144B rows, 16B-aligned

typedef _Float16 f16x8 __attribute__((ext_vector_type(8)));  // MFMA A/B frag
typedef float    f32x4 __attribute__((ext_vector_type(4)));  // MFMA C/D

__device__ __forceinline__ f16x8 splat8(float f) {
    _Float16 h = (_Float16)f;
    return (f16x8){h, h, h, h, h, h, h, h};
}

// ---------------------------------------------------------------------------
// Prep: zero-fill padded hx; fp16 weights, k-contiguous for MFMA A-frags.
//  wt_b [o<64][k2*64+c] = w_deform[o][c][k2]
//  wt_ob[oc<32][k2*64+c] = w_offset[oc][c][k2] (rows 18..31 zero)
// ---------------------------------------------------------------------------
#define HX_SEGS ((B_ * PR_ * PC_ * 64) / 8)   // 16B segments in hx
__global__ void prep(const float* __restrict__ wd,
                     const float* __restrict__ wo,
                     _Float16* __restrict__ wt_b,
                     _Float16* __restrict__ wt_ob,
                     _Float16* __restrict__ hx) {
    int gid = blockIdx.x * 256 + threadIdx.x;
    for (int i = gid; i < HX_SEGS; i += gridDim.x * 256)
        *(int4*)(hx + (size_t)i * 8) = make_int4(0, 0, 0, 0);
    if (gid < COUT_ * 576) {
        int o = gid / 576, rem = gid % 576;
        int k2 = rem >> 6, c = rem & 63;
        wt_b[gid] = (_Float16)wd[(o * CIN_ + c) * K2_ + k2];
    } else if (gid < COUT_ * 576 + 32 * 576) {
        int u = gid - COUT_ * 576;
        int oc = u / 576, rem = u % 576;
        int k2 = rem >> 6, c = rem & 63;
        wt_ob[u] = (_Float16)((oc < NOFF_) ? wo[(oc * CIN_ + c) * K2_ + k2] : 0.f);
    }
}

// ---------------------------------------------------------------------------
// x (NCHW fp32) -> hx (padded NHWC fp16). Block = (b, y) row; thread =
// (xpos, c-half). Reads wave-coalesced along W; writes 4x16B per thread.
// ---------------------------------------------------------------------------
__global__ __launch_bounds__(256) void x2h(const float* __restrict__ x,
                                           _Float16* __restrict__ hx) {
    const int blk = blockIdx.x;          // b*128 + y
    const int b = blk >> 7, y = blk & 127;
    const int xp = threadIdx.x & 127;
    const int ch = threadIdx.x >> 7;     // 0/1 -> channels 0-31 / 32-63
    const float* xs = x + ((b * CIN_ + ch * 32) * H_ + y) * W_ + xp;
    _Float16* hd = hx + (((size_t)b * PR_ + y + 2) * PC_ + xp + 3) * 64 + ch * 32;

    f16x8 h[4];
    #pragma unroll
    for (int j = 0; j < 4; ++j)
        #pragma unroll
        for (int t = 0; t < 8; ++t)
            h[j][t] = (_Float16)xs[(j * 8 + t) * HW_];
    #pragma unroll
    for (int j = 0; j < 4; ++j)
        *(f16x8*)(hd + j * 8) = h[j];
}

// ---------------------------------------------------------------------------
// Fused: stage hx tile -> offset conv (f16 MFMA) -> packed-f16 sampling ->
// deform f16 MFMA. Block = 64 px, 256 thr (4 waves), 2 blocks/CU.
// ---------------------------------------------------------------------------
__global__ __launch_bounds__(256) void deform_all(const _Float16* __restrict__ hx,
                                                  const _Float16* __restrict__ wt_b,
                                                  const _Float16* __restrict__ wt_ob,
                                                  float* __restrict__ out) {
    __shared__ _Float16 xt[TROWS * TCOLS * CPAD];   // 50.4 KB
    __shared__ float offs_l[NOFF_ * 64];            // 4.6 KB
    __shared__ _Float16 vtile[2][64 * CPAD];        // 18.4 KB

    const int tid = threadIdx.x;
    const int blk = blockIdx.x;            // (b*128 + oh)*2 + half
    const int b   = blk >> 8;
    const int r2  = blk & 255;
    const int oh  = r2 >> 1;
    const int ow0 = (r2 & 1) << 6;

    // ---- stage x tile: 2800 aligned 16B segments, no bounds checks ----
    // padded row for tile row r is oh+r; padded col for tile col 0 is ow0.
    const _Float16* hrow = hx + (((size_t)b * PR_ + oh) * PC_ + ow0) * 64;
    for (int i = tid; i < TROWS * TCOLS * 8; i += 256) {
        int r   = i / (TCOLS * 8);
        int rem = i - r * (TCOLS * 8);
        int col = rem >> 3;
        int cs  = rem & 7;
        f16x8 v = *(const f16x8*)(hrow + ((size_t)r * PC_ + col) * 64 + cs * 8);
        *(f16x8*)&xt[(r * TCOLS + col) * CPAD + cs * 8] = v;
    }
    __syncthreads();

    const int lane = tid & 63;
    const int cq   = tid >> 6;     // wave id
    const int quad = lane >> 4;
    const int nl   = lane & 15;

    // ---- offset conv via f16 MFMA: out[32 oc][64 px], K=576 ----
    f32x4 oacc[2];
    oacc[0] = (f32x4){0.f, 0.f, 0.f, 0.f};
    oacc[1] = (f32x4){0.f, 0.f, 0.f, 0.f};
    #pragma unroll
    for (int t9 = 0; t9 < 9; ++t9) {
        int ky = t9 / 3, kx = t9 - 3 * (t9 / 3);
        #pragma unroll
        for (int kb = 0; kb < 2; ++kb) {
            f16x8 bfr = *(const f16x8*)&xt[((ky + 1) * TCOLS + (cq * 16 + nl) + kx + 2) * CPAD + kb * 32 + quad * 8];
            #pragma unroll
            for (int mt = 0; mt < 2; ++mt) {
                f16x8 afr = *(const f16x8*)(wt_ob + (mt * 16 + nl) * 576 + t9 * 64 + kb * 32 + quad * 8);
                oacc[mt] = __builtin_amdgcn_mfma_f32_16x16x32_f16(afr, bfr, oacc[mt], 0, 0, 0);
            }
        }
    }
    #pragma unroll
    for (int mt = 0; mt < 2; ++mt)
        #pragma unroll
        for (int r = 0; r < 4; ++r) {
            int oc = mt * 16 + quad * 4 + r;
            if (oc < NOFF_) offs_l[oc * 64 + cq * 16 + nl] = oacc[mt][r];
        }
    __syncthreads();

    // ---- sampling (packed f16) + deform MFMA ----
    const int pix = tid & 63;
    const int ow  = ow0 + pix;

    f32x4 acc[4];
    #pragma unroll
    for (int mb = 0; mb < 4; ++mb) acc[mb] = (f32x4){0.f, 0.f, 0.f, 0.f};

    auto sample_k2 = [&](int k2, _Float16* vdst) {
        float dy = offs_l[(2 * k2 + 0) * 64 + pix];
        float dx = offs_l[(2 * k2 + 1) * 64 + pix];
        int ky = k2 / 3, kx = k2 - 3 * (k2 / 3);

        float py = (float)(oh - 1 + ky) + dy;
        float px = (float)(ow - 1 + kx) + dx;
        float y0f = floorf(py), x0f = floorf(px);
        float ly = py - y0f,    lx = px - x0f;
        int   y0 = (int)y0f,    x0 = (int)x0f;
        int   y1 = y0 + 1,      x1 = x0 + 1;

        float wy0 = 1.f - ly, wx0 = 1.f - lx;
        float w00 = wy0 * wx0, w01 = wy0 * lx, w10 = ly * wx0, w11 = ly * lx;

        bool vy0 = (unsigned)y0 < (unsigned)H_;
        bool vy1 = (unsigned)y1 < (unsigned)H_;
        bool vx0 = (unsigned)x0 < (unsigned)W_;
        bool vx1 = (unsigned)x1 < (unsigned)W_;
        if (!(vy0 & vx0)) w00 = 0.f;
        if (!(vy0 & vx1)) w01 = 0.f;
        if (!(vy1 & vx0)) w10 = 0.f;
        if (!(vy1 & vx1)) w11 = 0.f;

        f16x8 W00 = splat8(w00), W01 = splat8(w01), W10 = splat8(w10), W11 = splat8(w11);

        // tile coords (validity needed only when weight != 0)
        int ty0 = y0 - (oh - 2), ty1 = y1 - (oh - 2);
        int tx0 = x0 - (ow0 - 3), tx1 = x1 - (ow0 - 3);
        bool i00 = (unsigned)ty0 < TROWS && (unsigned)tx0 < TCOLS;
        bool i01 = (unsigned)ty0 < TROWS && (unsigned)tx1 < TCOLS;
        bool i10 = (unsigned)ty1 < TROWS && (unsigned)tx0 < TCOLS;
        bool i11 = (unsigned)ty1 < TROWS && (unsigned)tx1 < TCOLS;
        bool ok = (w00 == 0.f || i00) && (w01 == 0.f || i01) &&
                  (w10 == 0.f || i10) && (w11 == 0.f || i11);

        f16x8 v0, v1;
        if (ok) {
            int tyc0 = min(max(ty0, 0), TROWS - 1), tyc1 = min(max(ty1, 0), TROWS - 1);
            int txc0 = min(max(tx0, 0), TCOLS - 1), txc1 = min(max(tx1, 0), TCOLS - 1);
            int a00 = (tyc0 * TCOLS + txc0) * CPAD + cq * 16;
            int a01 = (tyc0 * TCOLS + txc1) * CPAD + cq * 16;
            int a10 = (tyc1 * TCOLS + txc0) * CPAD + cq * 16;
            int a11 = (tyc1 * TCOLS + txc1) * CPAD + cq * 16;
            f16x8 c00a = *(const f16x8*)&xt[a00], c00b = *(const f16x8*)&xt[a00 + 8];
            f16x8 c01a = *(const f16x8*)&xt[a01], c01b = *(const f16x8*)&xt[a01 + 8];
            f16x8 c10a = *(const f16x8*)&xt[a10], c10b = *(const f16x8*)&xt[a10 + 8];
            f16x8 c11a = *(const f16x8*)&xt[a11], c11b = *(const f16x8*)&xt[a11 + 8];
            v0 = c00a * W00 + c01a * W01 + c10a * W10 + c11a * W11;
            v1 = c00b * W00 + c01b * W01 + c10b * W10 + c11b * W11;
        } else {
            // rare fallback: image-clamped gather from padded hx
            int y0c = min(max(y0, 0), H_ - 1), y1c = min(max(y1, 0), H_ - 1);
            int x0c = min(max(x0, 0), W_ - 1), x1c = min(max(x1, 0), W_ - 1);
            const _Float16* hb = hx + (size_t)b * PR_ * PC_ * 64 + cq * 16;
            const _Float16* g00 = hb + (((y0c + 2) * PC_) + x0c + 3) * 64;
            const _Float16* g01 = hb + (((y0c + 2) * PC_) + x1c + 3) * 64;
            const _Float16* g10 = hb + (((y1c + 2) * PC_) + x0c + 3) * 64;
            const _Float16* g11 = hb + (((y1c + 2) * PC_) + x1c + 3) * 64;
            v0 = (*(const f16x8*)g00) * W00 + (*(const f16x8*)g01) * W01 +
                 (*(const f16x8*)g10) * W10 + (*(const f16x8*)g11) * W11;
            v1 = (*(const f16x8*)(g00 + 8)) * W00 + (*(const f16x8*)(g01 + 8)) * W01 +
                 (*(const f16x8*)(g10 + 8)) * W10 + (*(const f16x8*)(g11 + 8)) * W11;
        }
        *(f16x8*)&vdst[pix * CPAD + cq * 16]     = v0;
        *(f16x8*)&vdst[pix * CPAD + cq * 16 + 8] = v1;
    };

    sample_k2(0, vtile[0]);
    __syncthreads();

    for (int k2 = 0; k2 < K2_; ++k2) {
        if (k2 < K2_ - 1) sample_k2(k2 + 1, vtile[(k2 + 1) & 1]);
        const _Float16* vt = vtile[k2 & 1];
        #pragma unroll
        for (int kb = 0; kb < 2; ++kb) {
            f16x8 bfr = *(const f16x8*)&vt[(cq * 16 + nl) * CPAD + kb * 32 + quad * 8];
            #pragma unroll
            for (int mb = 0; mb < 4; ++mb) {
                f16x8 afr = *(const f16x8*)(wt_b + (mb * 16 + nl) * 576 + k2 * 64 + kb * 32 + quad * 8);
                acc[mb] = __builtin_amdgcn_mfma_f32_16x16x32_f16(afr, bfr, acc[mb], 0, 0, 0);
            }
        }
        __syncthreads();
    }

    // epilogue: C/D col = pixel (nl), row = quad*4 + r (verified layout)
    #pragma unroll
    for (int mb = 0; mb < 4; ++mb)
        #pragma unroll
        for (int r = 0; r < 4; ++r) {
            int o = mb * 16 + quad * 4 + r;
            out[(b * COUT_ + o) * HW_ + oh * W_ + ow0 + cq * 16 + nl] = acc[mb][r];
        }
}

// ---------------------------------------------------------------------------
extern "C" void kernel_launch(void* const* d_in, const int* in_sizes, int n_in,
                              void* d_out, int out_size, void* d_ws, size_t ws_size,
                              hipStream_t stream) {
    const float* x        = (const float*)d_in[0];  // (4, 64, 128, 128)
    const float* w_offset = (const float*)d_in[1];  // (18, 64, 3, 3)
    const float* w_deform = (const float*)d_in[2];  // (64, 64, 3, 3)
    float* out = (float*)d_out;                     // (4, 64, 128, 128)

    _Float16* hx    = (_Float16*)d_ws;                        // 4*132*136*64 halfs (9.2 MB)
    _Float16* wt_b  = hx + (size_t)B_ * PR_ * PC_ * 64;       // 64*576
    _Float16* wt_ob = wt_b + (size_t)COUT_ * 576;             // 32*576

    prep<<<256, 256, 0, stream>>>(w_deform, w_offset, wt_b, wt_ob, hx);
    x2h<<<B_ * H_, 256, 0, stream>>>(x, hx);
    deform_all<<<B_ * H_ * (W_ / 64), 256, 0, stream>>>(hx, wt_b, wt_ob, out);
}